// Round 11
// baseline (113.727 us; speedup 1.0000x reference)
//
#include <hip/hip_runtime.h>
#include <hip/hip_bf16.h>
#include <math.h>

// SelfRetentionV1: B=2,H=16,L=2048,DK=128,DV=128
// out[b,l,h,d] = RMSNorm_d( (QK^T * gamma^(i-j) / max(1,|rowsum|)) @ V )
#define B_ 2
#define H_ 16
#define L_ 2048
#define DK_ 128
#define DV_ 128
#define QBLK 64
#define KVBLK 64
#define NIT (L_/KVBLK)   // 32

typedef __bf16 bf16x8 __attribute__((ext_vector_type(8)));
typedef float  f32x16 __attribute__((ext_vector_type(16)));

static __device__ __forceinline__ unsigned short f2bf(float f) {
    union { float f; unsigned int u; } x; x.f = f;
    unsigned int r = x.u + 0x7fffu + ((x.u >> 16) & 1u);  // RNE
    return (unsigned short)(r >> 16);
}

// async global->LDS, 16B per lane; LDS dest = wave-uniform base + lane*16
static __device__ __forceinline__ void gload_lds16(const void* g, void* l) {
    __builtin_amdgcn_global_load_lds(
        (const __attribute__((address_space(1))) unsigned int*)g,
        (__attribute__((address_space(3))) unsigned int*)l,
        16, 0, 0);
}

// V tile rows are 128B: swizzle bits 4-6 by row&7 (involution)
#define VSWZ(d) ((d) ^ ((((d) >> 7) & 7) << 4))

// K fragment loads: direct global->VGPR via inline asm (compiler must not
// see these as tracked loads, or it inserts draining vmcnt(0) - m131/m141).
// One shared voffset VGPR + 13-bit immediate offsets.
#define KL1(dst, base, OFF)                                              \
    asm volatile("global_load_dwordx4 %0, %1, %2 offset:" #OFF           \
                 : "=&v"(dst) : "v"(kvoff), "s"(base))
#define KL8(arr, base)                                                   \
    KL1(arr[0], base, 0);   KL1(arr[1], base, 32);                       \
    KL1(arr[2], base, 64);  KL1(arr[3], base, 96);                       \
    KL1(arr[4], base, 128); KL1(arr[5], base, 160);                      \
    KL1(arr[6], base, 192); KL1(arr[7], base, 224)

// ---- fused pre-pass: blocks 0..1023 convert K fp32->bf16;
//      blocks 1024..2047 transpose V -> VT[bh][dv][perm(l)] (bit2<->3 perm
//      so P-register order == mfma k-slot order in PV) ----
__global__ void prep_kernel(const float* __restrict__ kin,
                            unsigned short* __restrict__ kb,
                            const float* __restrict__ v,
                            unsigned short* __restrict__ vt) {
    __shared__ unsigned short lds[64][130];   // +2 pad (transpose half only)
    int bid = blockIdx.x;
    if (bid < 1024) {
        int n4 = B_ * H_ * L_ * DK_ / 4;
        int i = bid * 256 + threadIdx.x;
        int stride = 1024 * 256;
        for (; i < n4; i += stride) {
            float4 f = ((const float4*)kin)[i];
            uint2 o;
            o.x = (unsigned)f2bf(f.x) | ((unsigned)f2bf(f.y) << 16);
            o.y = (unsigned)f2bf(f.z) | ((unsigned)f2bf(f.w) << 16);
            ((uint2*)kb)[i] = o;
        }
        return;
    }
    int blk = bid - 1024;
    int ltile = blk & (L_/64 - 1);
    int bh = blk / (L_/64);
    const float* vp = v + ((size_t)bh * L_ + (size_t)ltile * 64) * DV_;
    unsigned short* vo = vt + (size_t)bh * DV_ * L_ + ltile * 64;
    int t = threadIdx.x;
    int r0 = t >> 5, c0 = (t & 31) * 4;
    #pragma unroll
    for (int it = 0; it < 8; ++it) {
        int row = r0 + 8 * it;
        float4 f = *(const float4*)(vp + row * DV_ + c0);
        lds[row][c0 + 0] = f2bf(f.x);
        lds[row][c0 + 1] = f2bf(f.y);
        lds[row][c0 + 2] = f2bf(f.z);
        lds[row][c0 + 3] = f2bf(f.w);
    }
    __syncthreads();
    int dvb = t >> 3, seg = t & 7;
    #pragma unroll
    for (int ot = 0; ot < 4; ++ot) {
        int dv = dvb + 32 * ot;
        unsigned short a[8];
        #pragma unroll
        for (int tt = 0; tt < 8; ++tt) {
            int pp = seg * 8 + tt;
            int js = (pp & ~12) | ((pp & 4) << 1) | ((pp & 8) >> 1);  // swap b2,b3
            a[tt] = lds[js][dv];
        }
        uint4 st;
        st.x = (unsigned)a[0] | ((unsigned)a[1] << 16);
        st.y = (unsigned)a[2] | ((unsigned)a[3] << 16);
        st.z = (unsigned)a[4] | ((unsigned)a[5] << 16);
        st.w = (unsigned)a[6] | ((unsigned)a[7] << 16);
        *(uint4*)(vo + (size_t)dv * L_ + seg * 8) = st;
    }
}

// One pipeline round: consumes K-regs KC, prefetches K(jt+1) into KN.
// vmcnt(12) = this round issued 8 K-loads + 4 V-stages; everything older
// (KC's loads, V(jt)'s stage) is drained. sched_barrier(0) stops the
// compiler hoisting MFMAs above the wait (asm outputs aren't mem-ordered).
#define ROUND(KC, KN)                                                        \
{                                                                            \
    if (jt < itile) {                                                        \
        const unsigned short* kbase = kbp + (size_t)(jt + 1) * (KVBLK * DK_);\
        KL8(KN, kbase);                                                      \
        const char* vsrc = (const char*)(vtp + (jt + 1) * KVBLK);            \
        char* vdst = (char*)&vbuf[cur ^ 1][0];                               \
        gload_lds16(vsrc + voff[0], vdst + dwv[0]);                          \
        gload_lds16(vsrc + voff[1], vdst + dwv[1]);                          \
        gload_lds16(vsrc + voff[2], vdst + dwv[2]);                          \
        gload_lds16(vsrc + voff[3], vdst + dwv[3]);                          \
        asm volatile("s_waitcnt vmcnt(12)" ::: "memory");                    \
    } else {                                                                 \
        asm volatile("s_waitcnt vmcnt(0)" ::: "memory");                     \
    }                                                                        \
    asm volatile("s_barrier" ::: "memory");                                  \
    __builtin_amdgcn_sched_barrier(0);                                       \
    const char* vb_c = (const char*)&vbuf[cur][0];                           \
    f32x16 s;                                                                \
    _Pragma("unroll")                                                        \
    for (int e = 0; e < 16; ++e) s[e] = 0.0f;                                \
    _Pragma("unroll")                                                        \
    for (int ks = 0; ks < 8; ++ks)                                           \
        s = __builtin_amdgcn_mfma_f32_32x32x16_bf16(KC[ks], qf[ks], s, 0, 0, 0); \
    float ab = arow;                                                         \
    arow *= gm64i;                                                           \
    bool diag = (jt == itile);                                               \
    float v0[8];                                                             \
    if (diag) {                                                              \
        _Pragma("unroll")                                                    \
        for (int r = 0; r < 8; ++r) {                                        \
            float vv = s[r] * (colfac[r] * ab);                              \
            v0[r] = ((mbits >> r) & 1) ? vv : 0.0f;                          \
        }                                                                    \
    } else {                                                                 \
        _Pragma("unroll")                                                    \
        for (int r = 0; r < 8; ++r) v0[r] = s[r] * (colfac[r] * ab);         \
    }                                                                        \
    union { bf16x8 v; __bf16 e[8]; } P0;                                     \
    _Pragma("unroll")                                                        \
    for (int e = 0; e < 8; ++e) P0.e[e] = (__bf16)v0[e];                     \
    _Pragma("unroll")                                                        \
    for (int nt = 0; nt < 4; ++nt) {                                         \
        bf16x8 vb0 = *(const bf16x8*)(vb_c + (nt * 32 + il) * 128            \
                                      + ((kh * 64 + hl16) ^ rswz));          \
        o[nt] = __builtin_amdgcn_mfma_f32_32x32x16_bf16(P0.v, vb0, o[nt], 0, 0, 0); \
    }                                                                        \
    rowsum += ((v0[0] + v0[1]) + (v0[2] + v0[3]))                            \
            + ((v0[4] + v0[5]) + (v0[6] + v0[7]));                           \
    float v1[8];                                                             \
    if (diag) {                                                              \
        _Pragma("unroll")                                                    \
        for (int r = 0; r < 8; ++r) {                                        \
            float vv = s[r + 8] * (colfac[r + 8] * ab);                      \
            v1[r] = ((mbits >> (r + 8)) & 1) ? vv : 0.0f;                    \
        }                                                                    \
    } else {                                                                 \
        _Pragma("unroll")                                                    \
        for (int r = 0; r < 8; ++r) v1[r] = s[r + 8] * (colfac[r + 8] * ab); \
    }                                                                        \
    union { bf16x8 v; __bf16 e[8]; } P1;                                     \
    _Pragma("unroll")                                                        \
    for (int e = 0; e < 8; ++e) P1.e[e] = (__bf16)v1[e];                     \
    _Pragma("unroll")                                                        \
    for (int nt = 0; nt < 4; ++nt) {                                         \
        bf16x8 vb1 = *(const bf16x8*)(vb_c + (nt * 32 + il) * 128            \
                                      + ((kh * 64 + 32 + hl16) ^ rswz));     \
        o[nt] = __builtin_amdgcn_mfma_f32_32x32x16_bf16(P1.v, vb1, o[nt], 0, 0, 0); \
    }                                                                        \
    rowsum += ((v1[0] + v1[1]) + (v1[2] + v1[3]))                            \
            + ((v1[4] + v1[5]) + (v1[6] + v1[7]));                           \
    asm volatile("s_barrier" ::: "memory");                                  \
    cur ^= 1;                                                                \
}

// ---- main kernel: 4 waves (rh,kh); swapped QK^T, register P.
// K fragments DIRECT global->VGPR (inline asm, register double-buffer
// kA/kB via 2x-unrolled loop) -- K never touches LDS. V stays LDS-staged
// (dbuf, gload_lds). LDS traffic halves vs r10; the per-CU LDS pipe was
// the measured bound (~2050cy of the 2690cy round).
// Balanced schedule from r10: block = q-tiles {sp, 31-sp}, grid 512.
__launch_bounds__(256, 2)
__global__ void retention_kernel(const float* __restrict__ q,
                                 const unsigned short* __restrict__ kb,
                                 const unsigned short* __restrict__ vt_,
                                 float* __restrict__ out) {
    __shared__ __align__(16) unsigned short vbuf[2][128 * 64];   // 32 KB
    __shared__ float rsx[64];

    // bh->XCD-pinned remap (xcd = bid%8): 4 bh per XCD -> ~4MB K+V ~= L2
    int bid = blockIdx.x;            // 0..511
    int x   = bid & 7;               // XCD id
    int t_  = bid >> 3;              // 0..63
    int hi  = t_ >> 4;               // 0..3
    int sp  = t_ & 15;               // 0..15: q-tile pair (sp, 31-sp)
    int bh = hi * 8 + x;
    int b = bh >> 4, h = bh & 15;

    int tid = threadIdx.x;
    int lane = tid & 63;
    int w = tid >> 6;                   // 0..3
    int rh = w >> 1;                    // q-row half
    int kh = w & 1;                     // kv half
    int il = lane & 31;
    int hl = lane >> 5;

    const unsigned short* kbp = kb  + (size_t)bh * L_ * DK_;
    const unsigned short* vtp = vt_ + (size_t)bh * DV_ * L_;

    // per-lane V-stage offsets (loop-invariant)
    int dwv[4], voff[4];
    #pragma unroll
    for (int is = 0; is < 4; ++is) {
        int dw = is * 4096 + w * 1024;
        int d  = dw + lane * 16;
        dwv[is] = dw;
        int sv  = VSWZ(d);
        voff[is] = (sv >> 7) * (L_ * 2) + (sv & 127);
    }
    // K direct-load voffset: row (kh*32+il), byte hl*16; ks via offset: imm
    int kvoff = (kh * 32 + il) * 256 + hl * 16;

    float ex = exp2f((float)(-5 - h));
    float gamma = 1.0f - ex;
    float log2g = log1pf(-ex) * 1.44269504088896f;

    // colfac[r] = gamma^(-jr), jr = (r&3) + 8*(r>>2) + 4*hl
    float gi  = exp2f(-log2g);
    float gi2 = gi * gi, gi3 = gi2 * gi, gi4 = gi2 * gi2;
    float gi8 = gi4 * gi4, gi16 = gi8 * gi8, gi24 = gi16 * gi8;
    float cfq[4] = {1.f, gi, gi2, gi3};
    float cfp[4] = {1.f, gi8, gi16, gi24};
    float chl = hl ? gi4 : 1.f;
    float colfac[16];
    #pragma unroll
    for (int r = 0; r < 16; ++r) colfac[r] = cfq[r & 3] * cfp[r >> 2] * chl;

    float gm64i = exp2f(log2g * (-64.0f));
    int icmp = rh * 32 + il - kh * 32;   // diag mask: jr <= icmp (seg-invariant)
    unsigned mbits = 0;                  // bit r: keep reg r on diagonal tile
    #pragma unroll
    for (int r = 0; r < 16; ++r)
        if (((r & 3) + 8 * (r >> 2) + 4 * hl) <= icmp) mbits |= 1u << r;

    int rswz = (il & 7) << 4;           // V read-side XOR (rows == il mod 8)
    int hl16 = hl * 16;

    for (int seg = 0; seg < 2; ++seg) {
        int itile = seg ? (31 - sp) : sp;
        int i_base = itile * QBLK + rh * 32;
        int i_row  = i_base + il;       // this lane's q-row

        // ---- Q load + cvt FIRST (its waitcnt drains nothing of ours) ----
        bf16x8 qf[8];
        {
            const float* qp = q + ((size_t)bh * L_ + i_row) * DK_ + hl * 8;
            #pragma unroll
            for (int ks = 0; ks < 8; ++ks) {
                float4 f0 = *(const float4*)(qp + ks * 16);
                float4 f1 = *(const float4*)(qp + ks * 16 + 4);
                union { bf16x8 v; unsigned short u[8]; } A;
                A.u[0]=f2bf(f0.x); A.u[1]=f2bf(f0.y); A.u[2]=f2bf(f0.z); A.u[3]=f2bf(f0.w);
                A.u[4]=f2bf(f1.x); A.u[5]=f2bf(f1.y); A.u[6]=f2bf(f1.z); A.u[7]=f2bf(f1.w);
                qf[ks] = A.v;
            }
        }

        // ---- prologue: issue K(0)->kA (asm) + V(0)->vbuf[0] ----
        bf16x8 kA[8], kB[8];
        KL8(kA, kbp);
        {
            const char* vsrc = (const char*)vtp;
            char* vdst = (char*)&vbuf[0][0];
            #pragma unroll
            for (int is = 0; is < 4; ++is)
                gload_lds16(vsrc + voff[is], vdst + dwv[is]);
        }

        float arow = exp2f(log2g * (float)(i_row - kh * 32));

        f32x16 o[4];                    // O^T: lane = dv (il), regs = i-pattern
        #pragma unroll
        for (int nt = 0; nt < 4; ++nt)
            #pragma unroll
            for (int e = 0; e < 16; ++e) o[nt][e] = 0.0f;
        float rowsum = 0.0f;

        int cur = 0;
        int jt = 0;
        while (true) {                   // static kA/kB alternation (rule #20)
            ROUND(kA, kB);
            if (++jt > itile) break;
            ROUND(kB, kA);
            if (++jt > itile) break;
        }

        // ---- rowsum: combine hl halves ----
        float rsw = rowsum + __shfl_xor(rowsum, 32);

        // ---- cross-kh reduction via LDS (vbuf dead now -> exch) ----
        __syncthreads();   // all tile reads done before buffer reuse
        float* exch = (float*)&vbuf[0][0];   // 32KB: rh pairs at +rh*4096 floats
        if (kh == 1) {
            float* eb = exch + rh * 4096;
            #pragma unroll
            for (int nt = 0; nt < 4; ++nt)
                #pragma unroll
                for (int qq = 0; qq < 4; ++qq) {
                    float4 vv = { o[nt][4*qq+0], o[nt][4*qq+1],
                                  o[nt][4*qq+2], o[nt][4*qq+3] };
                    *(float4*)(eb + (nt * 4 + qq) * 256 + lane * 4) = vv;
                }
            if (lane < 32) rsx[rh * 32 + lane] = rsw;
        }
        __syncthreads();
        if (kh == 0) {
            float* eb = exch + rh * 4096;
            #pragma unroll
            for (int nt = 0; nt < 4; ++nt)
                #pragma unroll
                for (int qq = 0; qq < 4; ++qq) {
                    float4 pv = *(const float4*)(eb + (nt * 4 + qq) * 256 + lane * 4);
                    o[nt][4*qq+0] += pv.x; o[nt][4*qq+1] += pv.y;
                    o[nt][4*qq+2] += pv.z; o[nt][4*qq+3] += pv.w;
                }
            float rtot = rsw + rsx[rh * 32 + il];
            float dnl = 1.0f / fmaxf(1.0f, fabsf(rtot));

            #pragma unroll
            for (int r = 0; r < 16; ++r) {
                int isrc = (r & 3) + 8 * (r >> 2) + 4 * hl;   // i_local of reg r
                float dn = __shfl(dnl, isrc);
                float ov[4];
                float ss = 0.0f;
                #pragma unroll
                for (int nt = 0; nt < 4; ++nt) { ov[nt] = o[nt][r] * dn; ss += ov[nt] * ov[nt]; }
                ss += __shfl_xor(ss, 1);
                ss += __shfl_xor(ss, 2);
                ss += __shfl_xor(ss, 4);
                ss += __shfl_xor(ss, 8);
                ss += __shfl_xor(ss, 16);
                float sc = rsqrtf(ss * (1.0f / 128.0f) + 1e-6f);
                int i_abs = i_base + isrc;
                float* op = out + (((size_t)b * L_ + i_abs) * H_ + h) * DV_ + il;
                #pragma unroll
                for (int nt = 0; nt < 4; ++nt) op[nt * 32] = ov[nt] * sc;
            }
        }
        __syncthreads();   // exch reads done before next segment's staging
    }
}

// ---- fp32 fixup for row i=0 (single-term row: eps-magnified bf16 error) ----
__global__ void fix_row0_kernel(const float* __restrict__ q,
                                const float* __restrict__ k,
                                const float* __restrict__ v,
                                float* __restrict__ out) {
    int bh = blockIdx.x;            // 0..31
    int lane = threadIdx.x;         // 0..63
    const float* qp = q + (size_t)bh * L_ * DK_;
    const float* kp = k + (size_t)bh * L_ * DK_;
    const float* vp = v + (size_t)bh * L_ * DV_;
    float part = qp[lane] * kp[lane] + qp[lane + 64] * kp[lane + 64];
    #pragma unroll
    for (int mm = 1; mm < 64; mm <<= 1) part += __shfl_xor(part, mm);
    float r00 = part;
    float cf = r00 / fmaxf(1.0f, fabsf(r00));
    float o0 = cf * vp[lane], o1 = cf * vp[lane + 64];
    float ss = o0 * o0 + o1 * o1;
    #pragma unroll
    for (int mm = 1; mm < 64; mm <<= 1) ss += __shfl_xor(ss, mm);
    float sc = rsqrtf(ss * (1.0f / 128.0f) + 1e-6f);
    int b = bh >> 4, h = bh & 15;
    float* op = out + ((size_t)b * L_ * H_ + h) * DV_;   // i = 0
    op[lane] = o0 * sc;
    op[lane + 64] = o1 * sc;
}

extern "C" void kernel_launch(void* const* d_in, const int* in_sizes, int n_in,
                              void* d_out, int out_size, void* d_ws, size_t ws_size,
                              hipStream_t stream) {
    const float* q = (const float*)d_in[0];
    const float* k = (const float*)d_in[1];
    const float* v = (const float*)d_in[2];
    // d_in[3] decay_mask (256MB) and d_in[4] intra_decay are recomputed on the fly
    float* out = (float*)d_out;

    unsigned short* kb = (unsigned short*)d_ws;                 // 16 MB
    unsigned short* vt = kb + (size_t)B_ * H_ * L_ * DK_;       // 16 MB

    prep_kernel<<<2048, 256, 0, stream>>>(k, kb, v, vt);
    retention_kernel<<<512, 256, 0, stream>>>(q, kb, vt, out);
    fix_row0_kernel<<<B_ * H_, 64, 0, stream>>>(q, k, v, out);
}

// Round 12
// 96.969 us; speedup vs baseline: 1.1728x; 1.1728x over previous
//
#include <hip/hip_runtime.h>
#include <hip/hip_bf16.h>
#include <math.h>

// SelfRetentionV1: B=2,H=16,L=2048,DK=128,DV=128
// out[b,l,h,d] = RMSNorm_d( (QK^T * gamma^(i-j) / max(1,|rowsum|)) @ V )
#define B_ 2
#define H_ 16
#define L_ 2048
#define DK_ 128
#define DV_ 128
#define QBLK 128
#define KVBLK 64

typedef __bf16 bf16x8 __attribute__((ext_vector_type(8)));
typedef float  f32x16 __attribute__((ext_vector_type(16)));

static __device__ __forceinline__ unsigned short f2bf(float f) {
    union { float f; unsigned int u; } x; x.f = f;
    unsigned int r = x.u + 0x7fffu + ((x.u >> 16) & 1u);  // RNE
    return (unsigned short)(r >> 16);
}

// async global->LDS, 16B per lane; LDS dest = wave-uniform base + lane*16
static __device__ __forceinline__ void gload_lds16(const void* g, void* l) {
    __builtin_amdgcn_global_load_lds(
        (const __attribute__((address_space(1))) unsigned int*)g,
        (__attribute__((address_space(3))) unsigned int*)l,
        16, 0, 0);
}

// K tile rows are 256B: swizzle bits 4-6 by row&7 (involution, row bits >=8)
#define KSWZ(d) ((d) ^ ((((d) >> 8) & 7) << 4))
// V tile rows are 128B: row bits >=7
#define VSWZ(d) ((d) ^ ((((d) >> 7) & 7) << 4))

// ---- fused pre-pass: blocks 0..1023 convert K fp32->bf16; 1024..2047
// transpose V -> VT[bh][dv][perm(l)] (bit2<->3 perm); 2048..2079 do the
// fp32 row-0 fixup (retention skips its row-0 store; this runs first) ----
__global__ void prep_kernel(const float* __restrict__ kin,
                            unsigned short* __restrict__ kb,
                            const float* __restrict__ v,
                            unsigned short* __restrict__ vt,
                            const float* __restrict__ q,
                            float* __restrict__ out) {
    __shared__ unsigned short lds[64][130];   // +2 pad (transpose half only)
    int bid = blockIdx.x;
    if (bid >= 2048) {                 // row-0 fixup, 32 blocks, wave 0 only
        if (threadIdx.x < 64) {
            int bh = bid - 2048;
            int lane = threadIdx.x;
            const float* qp = q   + (size_t)bh * L_ * DK_;
            const float* kp = kin + (size_t)bh * L_ * DK_;
            const float* vp = v   + (size_t)bh * L_ * DV_;
            float part = qp[lane] * kp[lane] + qp[lane + 64] * kp[lane + 64];
            #pragma unroll
            for (int mm = 1; mm < 64; mm <<= 1) part += __shfl_xor(part, mm);
            float cf = part / fmaxf(1.0f, fabsf(part));
            float o0 = cf * vp[lane], o1 = cf * vp[lane + 64];
            float ss = o0 * o0 + o1 * o1;
            #pragma unroll
            for (int mm = 1; mm < 64; mm <<= 1) ss += __shfl_xor(ss, mm);
            float sc = rsqrtf(ss * (1.0f / 128.0f) + 1e-6f);
            int b = bh >> 4, h = bh & 15;
            float* op = out + ((size_t)b * L_ * H_ + h) * DV_;   // i = 0
            op[lane] = o0 * sc;
            op[lane + 64] = o1 * sc;
        }
        return;
    }
    if (bid < 1024) {
        int n4 = B_ * H_ * L_ * DK_ / 4;
        int i = bid * 256 + threadIdx.x;
        int stride = 1024 * 256;
        for (; i < n4; i += stride) {
            float4 f = ((const float4*)kin)[i];
            uint2 o;
            o.x = (unsigned)f2bf(f.x) | ((unsigned)f2bf(f.y) << 16);
            o.y = (unsigned)f2bf(f.z) | ((unsigned)f2bf(f.w) << 16);
            ((uint2*)kb)[i] = o;
        }
        return;
    }
    int blk = bid - 1024;
    int ltile = blk & (L_/64 - 1);
    int bh = blk / (L_/64);
    const float* vp = v + ((size_t)bh * L_ + (size_t)ltile * 64) * DV_;
    unsigned short* vo = vt + (size_t)bh * DV_ * L_ + ltile * 64;
    int t = threadIdx.x;
    int r0 = t >> 5, c0 = (t & 31) * 4;
    #pragma unroll
    for (int it = 0; it < 8; ++it) {
        int row = r0 + 8 * it;
        float4 f = *(const float4*)(vp + row * DV_ + c0);
        lds[row][c0 + 0] = f2bf(f.x);
        lds[row][c0 + 1] = f2bf(f.y);
        lds[row][c0 + 2] = f2bf(f.z);
        lds[row][c0 + 3] = f2bf(f.w);
    }
    __syncthreads();
    int dvb = t >> 3, seg = t & 7;
    #pragma unroll
    for (int ot = 0; ot < 4; ++ot) {
        int dv = dvb + 32 * ot;
        unsigned short a[8];
        #pragma unroll
        for (int tt = 0; tt < 8; ++tt) {
            int pp = seg * 8 + tt;
            int js = (pp & ~12) | ((pp & 4) << 1) | ((pp & 8) >> 1);  // swap b2,b3
            a[tt] = lds[js][dv];
        }
        uint4 st;
        st.x = (unsigned)a[0] | ((unsigned)a[1] << 16);
        st.y = (unsigned)a[2] | ((unsigned)a[3] << 16);
        st.z = (unsigned)a[4] | ((unsigned)a[5] << 16);
        st.w = (unsigned)a[6] | ((unsigned)a[7] << 16);
        *(uint4*)(vo + (size_t)dv * L_ + seg * 8) = st;
    }
}

// ---- main kernel: 4 waves = (qh x kh); each wave 64q x 32kv -> K/V frags
// reused across two q-sub-blocks: LDS bytes per q*kv unit HALVE vs r10.
// QBLK=128, q-tile pairs {sp,15-sp} => 34 rounds/block, grid 256 = 1/CU,
// 1 wave/SIMD with doubled per-wave ILP (2 indep QK chains, 32 MFMA/round).
// launch_bounds(256,1) unlocks the full VGPR file (~300 regs, no spill).
// Round protocol = proven r10: K/V dbuf, stage-at-top, vmcnt(8), 2 barriers.
__launch_bounds__(256, 1)
__global__ void retention_kernel(const float* __restrict__ q,
                                 const unsigned short* __restrict__ kb,
                                 const unsigned short* __restrict__ vt_,
                                 float* __restrict__ out) {
    __shared__ __align__(16) unsigned short kbuf[2][64 * 128];   // 32 KB
    __shared__ __align__(16) unsigned short vbuf[2][128 * 64];   // 32 KB
    __shared__ float rsx[128];

    // bh->XCD-pinned remap (xcd = bid%8): 4 bh per XCD -> ~4MB K+V ~= L2
    int bid = blockIdx.x;            // 0..255
    int x   = bid & 7;               // XCD id
    int sp  = (bid >> 3) & 7;        // 0..7: q-tile pair (sp, 15-sp)
    int hi  = bid >> 6;              // 0..3
    int bh = hi * 8 + x;
    int b = bh >> 4, h = bh & 15;

    int tid = threadIdx.x;
    int lane = tid & 63;
    int w = tid >> 6;                   // 0..3
    int qh = w >> 1;                    // q 64-row half
    int kh = w & 1;                     // kv half
    int il = lane & 31;
    int hl = lane >> 5;

    const unsigned short* kbp = kb  + (size_t)bh * L_ * DK_;
    const unsigned short* vtp = vt_ + (size_t)bh * DV_ * L_;

    // hoisted per-lane stage offsets (loop-invariant)
    int dwv[4], koff[4], voff[4];
    #pragma unroll
    for (int is = 0; is < 4; ++is) {
        int dw = is * 4096 + w * 1024;
        int d  = dw + lane * 16;
        dwv[is]  = dw;
        koff[is] = KSWZ(d);
        int sv   = VSWZ(d);
        voff[is] = (sv >> 7) * (L_ * 2) + (sv & 127);
    }

    float ex = exp2f((float)(-5 - h));
    float gamma = 1.0f - ex;
    float log2g = log1pf(-ex) * 1.44269504088896f;

    // colfac[r] = gamma^(-jr), jr = (r&3) + 8*(r>>2) + 4*hl
    float gi  = exp2f(-log2g);
    float gi2 = gi * gi, gi3 = gi2 * gi, gi4 = gi2 * gi2;
    float gi8 = gi4 * gi4, gi16 = gi8 * gi8, gi24 = gi16 * gi8;
    float cfq[4] = {1.f, gi, gi2, gi3};
    float cfp[4] = {1.f, gi8, gi16, gi24};
    float chl = hl ? gi4 : 1.f;
    float colfac[16];
    #pragma unroll
    for (int r = 0; r < 16; ++r) colfac[r] = cfq[r & 3] * cfp[r >> 2] * chl;

    float gm64i = exp2f(log2g * (-64.0f));
    float g32   = exp2f(log2g * 32.0f);

    int rswz = (il & 7) << 4;           // read-side XOR (rows == il mod 8)
    int krow256 = (kh * 32 + il) * 256;
    int hl16 = hl * 16;

    for (int seg = 0; seg < 2; ++seg) {
        int itile = seg ? (15 - sp) : sp;       // q-tile of 128 rows
        int jmax  = 2 * itile + 1;              // kv tiles 0..jmax
        int i0a = itile * QBLK + qh * 64;       // q-sub-block 0 base
        int i0b = i0a + 32;                     // q-sub-block 1 base

        // ---- Q fragments for both q-sub-blocks (B-operand, col = il) ----
        bf16x8 qfa[8], qfb[8];
        {
            const float* qpa = q + ((size_t)bh * L_ + (i0a + il)) * DK_ + hl * 8;
            const float* qpb = q + ((size_t)bh * L_ + (i0b + il)) * DK_ + hl * 8;
            #pragma unroll
            for (int ks = 0; ks < 8; ++ks) {
                float4 f0 = *(const float4*)(qpa + ks * 16);
                float4 f1 = *(const float4*)(qpa + ks * 16 + 4);
                union { bf16x8 v; unsigned short u[8]; } A;
                A.u[0]=f2bf(f0.x); A.u[1]=f2bf(f0.y); A.u[2]=f2bf(f0.z); A.u[3]=f2bf(f0.w);
                A.u[4]=f2bf(f1.x); A.u[5]=f2bf(f1.y); A.u[6]=f2bf(f1.z); A.u[7]=f2bf(f1.w);
                qfa[ks] = A.v;
                float4 g0 = *(const float4*)(qpb + ks * 16);
                float4 g1 = *(const float4*)(qpb + ks * 16 + 4);
                union { bf16x8 v; unsigned short u[8]; } Bu;
                Bu.u[0]=f2bf(g0.x); Bu.u[1]=f2bf(g0.y); Bu.u[2]=f2bf(g0.z); Bu.u[3]=f2bf(g0.w);
                Bu.u[4]=f2bf(g1.x); Bu.u[5]=f2bf(g1.y); Bu.u[6]=f2bf(g1.z); Bu.u[7]=f2bf(g1.w);
                qfb[ks] = Bu.v;
            }
        }

        // ---- stage tile 0 ----
        {
            const char* ksrc = (const char*)kbp;
            const char* vsrc = (const char*)vtp;
            #pragma unroll
            for (int is = 0; is < 4; ++is) {
                gload_lds16(ksrc + koff[is], (char*)&kbuf[0][0] + dwv[is]);
                gload_lds16(vsrc + voff[is], (char*)&vbuf[0][0] + dwv[is]);
            }
        }

        float arowA = exp2f(log2g * (float)(i0a + il - kh * 32));
        float arowB = arowA * g32;

        f32x16 oa[4], ob[4];
        #pragma unroll
        for (int nt = 0; nt < 4; ++nt)
            #pragma unroll
            for (int e = 0; e < 16; ++e) { oa[nt][e] = 0.0f; ob[nt][e] = 0.0f; }
        float rowsumA = 0.0f, rowsumB = 0.0f;

        int cur = 0;
        for (int jt = 0; jt <= jmax; ++jt) {
            if (jt < jmax) {
                const char* ksrc = (const char*)(kbp + (size_t)(jt + 1) * KVBLK * DK_);
                const char* vsrc = (const char*)(vtp + (jt + 1) * KVBLK);
                char* kdst = (char*)&kbuf[cur ^ 1][0];
                char* vdst = (char*)&vbuf[cur ^ 1][0];
                #pragma unroll
                for (int is = 0; is < 4; ++is) {
                    gload_lds16(ksrc + koff[is], kdst + dwv[is]);
                    gload_lds16(vsrc + voff[is], vdst + dwv[is]);
                }
                asm volatile("s_waitcnt vmcnt(8)" ::: "memory");
            } else {
                asm volatile("s_waitcnt vmcnt(0)" ::: "memory");
            }
            asm volatile("s_barrier" ::: "memory");

            const char* kb_c = (const char*)&kbuf[cur][0];
            const char* vb_c = (const char*)&vbuf[cur][0];

            // ---- S^T = mfma(K, Q): K frag read ONCE, feeds both q-chains ----
            f32x16 sA, sB;
            #pragma unroll
            for (int e = 0; e < 16; ++e) { sA[e] = 0.0f; sB[e] = 0.0f; }
            #pragma unroll
            for (int ks = 0; ks < 8; ++ks) {
                bf16x8 kf = *(const bf16x8*)(kb_c + krow256 + ((ks * 32 + hl16) ^ rswz));
                sA = __builtin_amdgcn_mfma_f32_32x32x16_bf16(kf, qfa[ks], sA, 0, 0, 0);
                sB = __builtin_amdgcn_mfma_f32_32x32x16_bf16(kf, qfb[ks], sB, 0, 0, 0);
            }

            int jb = jt * KVBLK + kh * 32;

            // ---- decay + mask + rowsum + pack, q-sub-block A ----
            float vA[16];
            if ((jt + 1) * KVBLK > i0a) {       // boundary/masked tiles
                int icmp = i0a + il - jb;
                #pragma unroll
                for (int r = 0; r < 16; ++r) {
                    int jr = (r & 3) + 8 * (r >> 2) + 4 * hl;
                    float vv = sA[r] * (colfac[r] * arowA);
                    vA[r] = (jr <= icmp) ? vv : 0.0f;
                }
            } else {
                #pragma unroll
                for (int r = 0; r < 16; ++r) vA[r] = sA[r] * (colfac[r] * arowA);
            }
            union { bf16x8 v; __bf16 e[8]; } PA0, PA1;
            #pragma unroll
            for (int e = 0; e < 8; ++e) { PA0.e[e] = (__bf16)vA[e]; PA1.e[e] = (__bf16)vA[8 + e]; }
            rowsumA += (((vA[0]+vA[1])+(vA[2]+vA[3]))+((vA[4]+vA[5])+(vA[6]+vA[7])))
                     + (((vA[8]+vA[9])+(vA[10]+vA[11]))+((vA[12]+vA[13])+(vA[14]+vA[15])));

            // ---- q-sub-block B ----
            float vB[16];
            if ((jt + 1) * KVBLK > i0b) {
                int icmp = i0b + il - jb;
                #pragma unroll
                for (int r = 0; r < 16; ++r) {
                    int jr = (r & 3) + 8 * (r >> 2) + 4 * hl;
                    float vv = sB[r] * (colfac[r] * arowB);
                    vB[r] = (jr <= icmp) ? vv : 0.0f;
                }
            } else {
                #pragma unroll
                for (int r = 0; r < 16; ++r) vB[r] = sB[r] * (colfac[r] * arowB);
            }
            union { bf16x8 v; __bf16 e[8]; } PB0, PB1;
            #pragma unroll
            for (int e = 0; e < 8; ++e) { PB0.e[e] = (__bf16)vB[e]; PB1.e[e] = (__bf16)vB[8 + e]; }
            rowsumB += (((vB[0]+vB[1])+(vB[2]+vB[3]))+((vB[4]+vB[5])+(vB[6]+vB[7])))
                     + (((vB[8]+vB[9])+(vB[10]+vB[11]))+((vB[12]+vB[13])+(vB[14]+vB[15])));

            arowA *= gm64i;
            arowB *= gm64i;

            // ---- PV: V frag read ONCE, feeds both q-sub-blocks ----
            #pragma unroll
            for (int nt = 0; nt < 4; ++nt) {
                bf16x8 vb0 = *(const bf16x8*)(vb_c + (nt * 32 + il) * 128
                                              + ((kh * 64 + hl16) ^ rswz));
                oa[nt] = __builtin_amdgcn_mfma_f32_32x32x16_bf16(PA0.v, vb0, oa[nt], 0, 0, 0);
                ob[nt] = __builtin_amdgcn_mfma_f32_32x32x16_bf16(PB0.v, vb0, ob[nt], 0, 0, 0);
                bf16x8 vb1 = *(const bf16x8*)(vb_c + (nt * 32 + il) * 128
                                              + ((kh * 64 + 32 + hl16) ^ rswz));
                oa[nt] = __builtin_amdgcn_mfma_f32_32x32x16_bf16(PA1.v, vb1, oa[nt], 0, 0, 0);
                ob[nt] = __builtin_amdgcn_mfma_f32_32x32x16_bf16(PB1.v, vb1, ob[nt], 0, 0, 0);
            }

            asm volatile("s_barrier" ::: "memory");
            cur ^= 1;
        }

        // ---- rowsum: combine hl halves ----
        float rswA = rowsumA + __shfl_xor(rowsumA, 32);
        float rswB = rowsumB + __shfl_xor(rowsumB, 32);

        // ---- cross-kh reduction via LDS (tile buffers dead now) ----
        __syncthreads();
        float* eb = (qh == 0) ? (float*)&kbuf[0][0] : (float*)&vbuf[0][0];
        if (kh == 1) {
            #pragma unroll
            for (int nt = 0; nt < 4; ++nt)
                #pragma unroll
                for (int qq = 0; qq < 4; ++qq) {
                    float4 va = { oa[nt][4*qq+0], oa[nt][4*qq+1],
                                  oa[nt][4*qq+2], oa[nt][4*qq+3] };
                    *(float4*)(eb + (nt * 4 + qq) * 256 + lane * 4) = va;
                    float4 vb = { ob[nt][4*qq+0], ob[nt][4*qq+1],
                                  ob[nt][4*qq+2], ob[nt][4*qq+3] };
                    *(float4*)(eb + (16 + nt * 4 + qq) * 256 + lane * 4) = vb;
                }
            if (lane < 32) {
                rsx[qh * 64 + lane]      = rswA;
                rsx[qh * 64 + 32 + lane] = rswB;
            }
        }
        __syncthreads();
        if (kh == 0) {
            #pragma unroll
            for (int nt = 0; nt < 4; ++nt)
                #pragma unroll
                for (int qq = 0; qq < 4; ++qq) {
                    float4 pa = *(const float4*)(eb + (nt * 4 + qq) * 256 + lane * 4);
                    oa[nt][4*qq+0] += pa.x; oa[nt][4*qq+1] += pa.y;
                    oa[nt][4*qq+2] += pa.z; oa[nt][4*qq+3] += pa.w;
                    float4 pb = *(const float4*)(eb + (16 + nt * 4 + qq) * 256 + lane * 4);
                    ob[nt][4*qq+0] += pb.x; ob[nt][4*qq+1] += pb.y;
                    ob[nt][4*qq+2] += pb.z; ob[nt][4*qq+3] += pb.w;
                }
            float rtotA = rswA + rsx[qh * 64 + il];
            float rtotB = rswB + rsx[qh * 64 + 32 + il];
            float dnlA = 1.0f / fmaxf(1.0f, fabsf(rtotA));
            float dnlB = 1.0f / fmaxf(1.0f, fabsf(rtotB));

            #pragma unroll
            for (int r = 0; r < 16; ++r) {
                int isrc = (r & 3) + 8 * (r >> 2) + 4 * hl;
                // q-sub-block A
                {
                    float dn = __shfl(dnlA, isrc);
                    float ov[4]; float ss = 0.0f;
                    #pragma unroll
                    for (int nt = 0; nt < 4; ++nt) { ov[nt] = oa[nt][r] * dn; ss += ov[nt]*ov[nt]; }
                    ss += __shfl_xor(ss, 1);  ss += __shfl_xor(ss, 2);
                    ss += __shfl_xor(ss, 4);  ss += __shfl_xor(ss, 8);
                    ss += __shfl_xor(ss, 16);
                    float sc = rsqrtf(ss * (1.0f / 128.0f) + 1e-6f);
                    int i_abs = i0a + isrc;
                    if (i_abs != 0) {            // row 0 handled in prep (fp32)
                        float* op = out + (((size_t)b * L_ + i_abs) * H_ + h) * DV_ + il;
                        #pragma unroll
                        for (int nt = 0; nt < 4; ++nt) op[nt * 32] = ov[nt] * sc;
                    }
                }
                // q-sub-block B
                {
                    float dn = __shfl(dnlB, isrc);
                    float ov[4]; float ss = 0.0f;
                    #pragma unroll
                    for (int nt = 0; nt < 4; ++nt) { ov[nt] = ob[nt][r] * dn; ss += ov[nt]*ov[nt]; }
                    ss += __shfl_xor(ss, 1);  ss += __shfl_xor(ss, 2);
                    ss += __shfl_xor(ss, 4);  ss += __shfl_xor(ss, 8);
                    ss += __shfl_xor(ss, 16);
                    float sc = rsqrtf(ss * (1.0f / 128.0f) + 1e-6f);
                    int i_abs = i0b + isrc;
                    float* op = out + (((size_t)b * L_ + i_abs) * H_ + h) * DV_ + il;
                    #pragma unroll
                    for (int nt = 0; nt < 4; ++nt) op[nt * 32] = ov[nt] * sc;
                }
            }
        }
        __syncthreads();   // exch reads done before next segment's staging
    }
}

extern "C" void kernel_launch(void* const* d_in, const int* in_sizes, int n_in,
                              void* d_out, int out_size, void* d_ws, size_t ws_size,
                              hipStream_t stream) {
    const float* q = (const float*)d_in[0];
    const float* k = (const float*)d_in[1];
    const float* v = (const float*)d_in[2];
    // d_in[3] decay_mask (256MB) and d_in[4] intra_decay are recomputed on the fly
    float* out = (float*)d_out;

    unsigned short* kb = (unsigned short*)d_ws;                 // 16 MB
    unsigned short* vt = kb + (size_t)B_ * H_ * L_ * DK_;       // 16 MB

    prep_kernel<<<2080, 256, 0, stream>>>(k, kb, v, vt, q, out);
    retention_kernel<<<256, 256, 0, stream>>>(q, kb, vt, out);
}

// Round 13
// 90.319 us; speedup vs baseline: 1.2592x; 1.0736x over previous
//
#include <hip/hip_runtime.h>
#include <hip/hip_bf16.h>
#include <math.h>

// SelfRetentionV1: B=2,H=16,L=2048,DK=128,DV=128
// out[b,l,h,d] = RMSNorm_d( (QK^T * gamma^(i-j) / max(1,|rowsum|)) @ V )
#define B_ 2
#define H_ 16
#define L_ 2048
#define DK_ 128
#define DV_ 128
#define QBLK 128
#define KVBLK 128

typedef __bf16 bf16x8 __attribute__((ext_vector_type(8)));
typedef float  f32x16 __attribute__((ext_vector_type(16)));

static __device__ __forceinline__ unsigned short f2bf(float f) {
    union { float f; unsigned int u; } x; x.f = f;
    unsigned int r = x.u + 0x7fffu + ((x.u >> 16) & 1u);  // RNE
    return (unsigned short)(r >> 16);
}

// async global->LDS, 16B per lane; LDS dest = wave-uniform base + lane*16
static __device__ __forceinline__ void gload_lds16(const void* g, void* l) {
    __builtin_amdgcn_global_load_lds(
        (const __attribute__((address_space(1))) unsigned int*)g,
        (__attribute__((address_space(3))) unsigned int*)l,
        16, 0, 0);
}

// Both K and V^T tiles now have 256B rows: swizzle bits 4-6 by row&7
#define SWZ(d) ((d) ^ ((((d) >> 8) & 7) << 4))

// ---- fused pre-pass: blocks 0..1023 convert K fp32->bf16; 1024..2047
// transpose V -> VT[bh][dv][perm(l)] (bit2<->3 perm); 2048..2079 do the
// fp32 row-0 fixup (retention skips its row-0 store) ----
__global__ void prep_kernel(const float* __restrict__ kin,
                            unsigned short* __restrict__ kb,
                            const float* __restrict__ v,
                            unsigned short* __restrict__ vt,
                            const float* __restrict__ q,
                            float* __restrict__ out) {
    __shared__ unsigned short lds[64][130];   // +2 pad (transpose half only)
    int bid = blockIdx.x;
    if (bid >= 2048) {                 // row-0 fixup, 32 blocks, wave 0 only
        if (threadIdx.x < 64) {
            int bh = bid - 2048;
            int lane = threadIdx.x;
            const float* qp = q   + (size_t)bh * L_ * DK_;
            const float* kp = kin + (size_t)bh * L_ * DK_;
            const float* vp = v   + (size_t)bh * L_ * DV_;
            float part = qp[lane] * kp[lane] + qp[lane + 64] * kp[lane + 64];
            #pragma unroll
            for (int mm = 1; mm < 64; mm <<= 1) part += __shfl_xor(part, mm);
            float cf = part / fmaxf(1.0f, fabsf(part));
            float o0 = cf * vp[lane], o1 = cf * vp[lane + 64];
            float ss = o0 * o0 + o1 * o1;
            #pragma unroll
            for (int mm = 1; mm < 64; mm <<= 1) ss += __shfl_xor(ss, mm);
            float sc = rsqrtf(ss * (1.0f / 128.0f) + 1e-6f);
            int b = bh >> 4, h = bh & 15;
            float* op = out + ((size_t)b * L_ * H_ + h) * DV_;   // i = 0
            op[lane] = o0 * sc;
            op[lane + 64] = o1 * sc;
        }
        return;
    }
    if (bid < 1024) {
        int n4 = B_ * H_ * L_ * DK_ / 4;
        int i = bid * 256 + threadIdx.x;
        int stride = 1024 * 256;
        for (; i < n4; i += stride) {
            float4 f = ((const float4*)kin)[i];
            uint2 o;
            o.x = (unsigned)f2bf(f.x) | ((unsigned)f2bf(f.y) << 16);
            o.y = (unsigned)f2bf(f.z) | ((unsigned)f2bf(f.w) << 16);
            ((uint2*)kb)[i] = o;
        }
        return;
    }
    int blk = bid - 1024;
    int ltile = blk & (L_/64 - 1);
    int bh = blk / (L_/64);
    const float* vp = v + ((size_t)bh * L_ + (size_t)ltile * 64) * DV_;
    unsigned short* vo = vt + (size_t)bh * DV_ * L_ + ltile * 64;
    int t = threadIdx.x;
    int r0 = t >> 5, c0 = (t & 31) * 4;
    #pragma unroll
    for (int it = 0; it < 8; ++it) {
        int row = r0 + 8 * it;
        float4 f = *(const float4*)(vp + row * DV_ + c0);
        lds[row][c0 + 0] = f2bf(f.x);
        lds[row][c0 + 1] = f2bf(f.y);
        lds[row][c0 + 2] = f2bf(f.z);
        lds[row][c0 + 3] = f2bf(f.w);
    }
    __syncthreads();
    int dvb = t >> 3, seg = t & 7;
    #pragma unroll
    for (int ot = 0; ot < 4; ++ot) {
        int dv = dvb + 32 * ot;
        unsigned short a[8];
        #pragma unroll
        for (int tt = 0; tt < 8; ++tt) {
            int pp = seg * 8 + tt;
            int js = (pp & ~12) | ((pp & 4) << 1) | ((pp & 8) >> 1);  // swap b2,b3
            a[tt] = lds[js][dv];
        }
        uint4 st;
        st.x = (unsigned)a[0] | ((unsigned)a[1] << 16);
        st.y = (unsigned)a[2] | ((unsigned)a[3] << 16);
        st.z = (unsigned)a[4] | ((unsigned)a[5] << 16);
        st.w = (unsigned)a[6] | ((unsigned)a[7] << 16);
        *(uint4*)(vo + (size_t)dv * L_ + seg * 8) = st;
    }
}

// ---- main kernel: 512 threads = 8 waves (qq 0..3 x kh 0..1), one block/CU.
// QBLK=KVBLK=128: per-CU rounds drop 66 -> 17 (4x bigger rounds) while
// occupancy stays 2 waves/SIMD -- amortizes the measured ~1400cy/round
// barrier+wait overhead 4x. LDS 128KB dbuf (64K K + 64K V).
// Per wave-round: 2 QK chains (kv 32-groups m=0,1) + 16 PV MFMA; K/V rows
// both 256B -> single SWZ/rswz scheme. Balance: q-tile pairs {sp,15-sp}
// => 17 rounds for every block; grid 256 = 1 block/CU, XCD-pinned bh.
__launch_bounds__(512, 2)
__global__ void retention_kernel(const float* __restrict__ q,
                                 const unsigned short* __restrict__ kb,
                                 const unsigned short* __restrict__ vt_,
                                 float* __restrict__ out) {
    __shared__ __align__(16) unsigned short kbuf[2][128 * 128];   // 64 KB
    __shared__ __align__(16) unsigned short vbuf[2][128 * 128];   // 64 KB
    __shared__ float rsx[128];

    // bh->XCD-pinned remap (xcd = bid%8): 4 bh per XCD -> ~4MB K+V ~= L2
    int bid = blockIdx.x;            // 0..255
    int x   = bid & 7;               // XCD id
    int sp  = (bid >> 3) & 7;        // 0..7: q-tile pair (sp, 15-sp)
    int hi  = bid >> 6;              // 0..3
    int bh = hi * 8 + x;
    int b = bh >> 4, h = bh & 15;

    int tid = threadIdx.x;
    int lane = tid & 63;
    int w = tid >> 6;                   // 0..7
    int qq = w >> 1;                    // q 32-row quarter
    int kh = w & 1;                     // kv 64-col half
    int il = lane & 31;
    int hl = lane >> 5;

    const unsigned short* kbp = kb  + (size_t)bh * L_ * DK_;
    const unsigned short* vtp = vt_ + (size_t)bh * DV_ * L_;

    // hoisted per-lane stage offsets (loop-invariant); tiles are 32KB,
    // 512 threads x 16B = 8KB/pass, 4 passes
    int dwv[4], koff[4], voff[4];
    #pragma unroll
    for (int is = 0; is < 4; ++is) {
        int dw = is * 8192 + w * 1024;
        int d  = dw + lane * 16;
        dwv[is]  = dw;
        koff[is] = SWZ(d);              // K tile is a flat 32KB chunk
        int sv   = SWZ(d);
        voff[is] = (sv >> 8) * (L_ * 2) + (sv & 255);   // V rows stride L*2
    }

    float ex = exp2f((float)(-5 - h));
    float gamma = 1.0f - ex;
    float log2g = log1pf(-ex) * 1.44269504088896f;

    // colfac[r] = gamma^(-jr), jr = (r&3) + 8*(r>>2) + 4*hl  (within 32-group)
    float gi  = exp2f(-log2g);
    float gi2 = gi * gi, gi3 = gi2 * gi, gi4 = gi2 * gi2;
    float gi8 = gi4 * gi4, gi16 = gi8 * gi8, gi24 = gi16 * gi8;
    float cfq[4] = {1.f, gi, gi2, gi3};
    float cfp[4] = {1.f, gi8, gi16, gi24};
    float chl = hl ? gi4 : 1.f;
    float colfac[16];
    #pragma unroll
    for (int r = 0; r < 16; ++r) colfac[r] = cfq[r & 3] * cfp[r >> 2] * chl;

    float gi32   = gi16 * gi16;
    float gm128i = exp2f(log2g * (-128.0f));

    // diag masks (segment-invariant): keep iff jr <= icmp
    int icmpA = qq * 32 + il - kh * 64;
    int icmpB = icmpA - 32;
    unsigned mbA = 0, mbB = 0;
    #pragma unroll
    for (int r = 0; r < 16; ++r) {
        int jr = (r & 3) + 8 * (r >> 2) + 4 * hl;
        if (jr <= icmpA) mbA |= 1u << r;
        if (jr <= icmpB) mbB |= 1u << r;
    }

    int rswz = (il & 7) << 4;           // read-side XOR (rows == il mod 8)
    int hl16 = hl * 16;

    for (int seg = 0; seg < 2; ++seg) {
        int itile = seg ? (15 - sp) : sp;       // q-tile of 128 rows
        int jmax  = itile;                      // kv tiles 0..jmax (128 each)
        int i0 = itile * QBLK + qq * 32;

        // ---- Q fragments FIRST (their waitcnt must not drain our stages) ----
        bf16x8 qf[8];
        {
            const float* qp = q + ((size_t)bh * L_ + (i0 + il)) * DK_ + hl * 8;
            #pragma unroll
            for (int ks = 0; ks < 8; ++ks) {
                float4 f0 = *(const float4*)(qp + ks * 16);
                float4 f1 = *(const float4*)(qp + ks * 16 + 4);
                union { bf16x8 v; unsigned short u[8]; } A;
                A.u[0]=f2bf(f0.x); A.u[1]=f2bf(f0.y); A.u[2]=f2bf(f0.z); A.u[3]=f2bf(f0.w);
                A.u[4]=f2bf(f1.x); A.u[5]=f2bf(f1.y); A.u[6]=f2bf(f1.z); A.u[7]=f2bf(f1.w);
                qf[ks] = A.v;
            }
        }

        // ---- stage tile 0 ----
        {
            const char* ksrc = (const char*)kbp;
            const char* vsrc = (const char*)vtp;
            #pragma unroll
            for (int is = 0; is < 4; ++is) {
                gload_lds16(ksrc + koff[is], (char*)&kbuf[0][0] + dwv[is]);
                gload_lds16(vsrc + voff[is], (char*)&vbuf[0][0] + dwv[is]);
            }
        }

        float arowA = exp2f(log2g * (float)(i0 + il - kh * 64));
        float arowB = arowA * gi32;

        f32x16 o[4];                    // O^T: lane = dv (il), regs = i-pattern
        #pragma unroll
        for (int nt = 0; nt < 4; ++nt)
            #pragma unroll
            for (int e = 0; e < 16; ++e) o[nt][e] = 0.0f;
        float rowsum = 0.0f;

        int cur = 0;
        for (int jt = 0; jt <= jmax; ++jt) {
            if (jt < jmax) {
                const char* ksrc = (const char*)(kbp + (size_t)(jt + 1) * KVBLK * DK_);
                const char* vsrc = (const char*)(vtp + (jt + 1) * KVBLK);
                char* kdst = (char*)&kbuf[cur ^ 1][0];
                char* vdst = (char*)&vbuf[cur ^ 1][0];
                #pragma unroll
                for (int is = 0; is < 4; ++is) {
                    gload_lds16(ksrc + koff[is], kdst + dwv[is]);
                    gload_lds16(vsrc + voff[is], vdst + dwv[is]);
                }
                asm volatile("s_waitcnt vmcnt(8)" ::: "memory");
            } else {
                asm volatile("s_waitcnt vmcnt(0)" ::: "memory");
            }
            asm volatile("s_barrier" ::: "memory");

            const char* kb_c = (const char*)&kbuf[cur][0];
            const char* vb_c = (const char*)&vbuf[cur][0];

            // ---- S^T: two kv-32-groups, independent chains; qf shared ----
            f32x16 sA, sB;
            #pragma unroll
            for (int e = 0; e < 16; ++e) { sA[e] = 0.0f; sB[e] = 0.0f; }
            #pragma unroll
            for (int ks = 0; ks < 8; ++ks) {
                bf16x8 kfA = *(const bf16x8*)(kb_c + (kh * 64 + il) * 256
                                              + ((ks * 32 + hl16) ^ rswz));
                bf16x8 kfB = *(const bf16x8*)(kb_c + (kh * 64 + 32 + il) * 256
                                              + ((ks * 32 + hl16) ^ rswz));
                sA = __builtin_amdgcn_mfma_f32_32x32x16_bf16(kfA, qf[ks], sA, 0, 0, 0);
                sB = __builtin_amdgcn_mfma_f32_32x32x16_bf16(kfB, qf[ks], sB, 0, 0, 0);
            }

            bool diag = (jt == jmax);

            // ---- decay + mask + rowsum + pack, m=0 ----
            float vA[16];
            if (diag) {
                #pragma unroll
                for (int r = 0; r < 16; ++r) {
                    float vv = sA[r] * (colfac[r] * arowA);
                    vA[r] = ((mbA >> r) & 1) ? vv : 0.0f;
                }
            } else {
                #pragma unroll
                for (int r = 0; r < 16; ++r) vA[r] = sA[r] * (colfac[r] * arowA);
            }
            union { bf16x8 v; __bf16 e[8]; } PA0, PA1;
            #pragma unroll
            for (int e = 0; e < 8; ++e) { PA0.e[e] = (__bf16)vA[e]; PA1.e[e] = (__bf16)vA[8 + e]; }
            rowsum += (((vA[0]+vA[1])+(vA[2]+vA[3]))+((vA[4]+vA[5])+(vA[6]+vA[7])))
                    + (((vA[8]+vA[9])+(vA[10]+vA[11]))+((vA[12]+vA[13])+(vA[14]+vA[15])));

            // ---- PV m=0 (overlaps m=1 VALU below) ----
            #pragma unroll
            for (int nt = 0; nt < 4; ++nt) {
                const char* base = vb_c + (nt * 32 + il) * 256;
                bf16x8 vb00 = *(const bf16x8*)(base + ((kh * 128 + hl16) ^ rswz));
                o[nt] = __builtin_amdgcn_mfma_f32_32x32x16_bf16(PA0.v, vb00, o[nt], 0, 0, 0);
                bf16x8 vb01 = *(const bf16x8*)(base + ((kh * 128 + 32 + hl16) ^ rswz));
                o[nt] = __builtin_amdgcn_mfma_f32_32x32x16_bf16(PA1.v, vb01, o[nt], 0, 0, 0);
            }

            // ---- decay + mask + rowsum + pack, m=1 ----
            float vB[16];
            if (diag) {
                #pragma unroll
                for (int r = 0; r < 16; ++r) {
                    float vv = sB[r] * (colfac[r] * arowB);
                    vB[r] = ((mbB >> r) & 1) ? vv : 0.0f;
                }
            } else {
                #pragma unroll
                for (int r = 0; r < 16; ++r) vB[r] = sB[r] * (colfac[r] * arowB);
            }
            union { bf16x8 v; __bf16 e[8]; } PB0, PB1;
            #pragma unroll
            for (int e = 0; e < 8; ++e) { PB0.e[e] = (__bf16)vB[e]; PB1.e[e] = (__bf16)vB[8 + e]; }
            rowsum += (((vB[0]+vB[1])+(vB[2]+vB[3]))+((vB[4]+vB[5])+(vB[6]+vB[7])))
                    + (((vB[8]+vB[9])+(vB[10]+vB[11]))+((vB[12]+vB[13])+(vB[14]+vB[15])));

            arowA *= gm128i;
            arowB *= gm128i;

            // ---- PV m=1 ----
            #pragma unroll
            for (int nt = 0; nt < 4; ++nt) {
                const char* base = vb_c + (nt * 32 + il) * 256;
                bf16x8 vb10 = *(const bf16x8*)(base + ((kh * 128 + 64 + hl16) ^ rswz));
                o[nt] = __builtin_amdgcn_mfma_f32_32x32x16_bf16(PB0.v, vb10, o[nt], 0, 0, 0);
                bf16x8 vb11 = *(const bf16x8*)(base + ((kh * 128 + 96 + hl16) ^ rswz));
                o[nt] = __builtin_amdgcn_mfma_f32_32x32x16_bf16(PB1.v, vb11, o[nt], 0, 0, 0);
            }

            asm volatile("s_barrier" ::: "memory");
            cur ^= 1;
        }

        // ---- rowsum: combine hl halves ----
        float rsw = rowsum + __shfl_xor(rowsum, 32);

        // ---- cross-kh reduction via LDS (tile buffers dead now) ----
        __syncthreads();
        float* eb = (float*)&kbuf[0][0] + qq * 4096;   // 16KB per quarter
        if (kh == 1) {
            #pragma unroll
            for (int nt = 0; nt < 4; ++nt)
                #pragma unroll
                for (int qg = 0; qg < 4; ++qg) {
                    float4 vv = { o[nt][4*qg+0], o[nt][4*qg+1],
                                  o[nt][4*qg+2], o[nt][4*qg+3] };
                    *(float4*)(eb + (nt * 4 + qg) * 256 + lane * 4) = vv;
                }
            if (lane < 32) rsx[qq * 32 + lane] = rsw;
        }
        __syncthreads();
        if (kh == 0) {
            #pragma unroll
            for (int nt = 0; nt < 4; ++nt)
                #pragma unroll
                for (int qg = 0; qg < 4; ++qg) {
                    float4 pv = *(const float4*)(eb + (nt * 4 + qg) * 256 + lane * 4);
                    o[nt][4*qg+0] += pv.x; o[nt][4*qg+1] += pv.y;
                    o[nt][4*qg+2] += pv.z; o[nt][4*qg+3] += pv.w;
                }
            float rtot = rsw + rsx[qq * 32 + il];
            float dnl = 1.0f / fmaxf(1.0f, fabsf(rtot));

            #pragma unroll
            for (int r = 0; r < 16; ++r) {
                int isrc = (r & 3) + 8 * (r >> 2) + 4 * hl;
                float dn = __shfl(dnl, isrc);
                float ov[4]; float ss = 0.0f;
                #pragma unroll
                for (int nt = 0; nt < 4; ++nt) { ov[nt] = o[nt][r] * dn; ss += ov[nt]*ov[nt]; }
                ss += __shfl_xor(ss, 1);  ss += __shfl_xor(ss, 2);
                ss += __shfl_xor(ss, 4);  ss += __shfl_xor(ss, 8);
                ss += __shfl_xor(ss, 16);
                float sc = rsqrtf(ss * (1.0f / 128.0f) + 1e-6f);
                int i_abs = i0 + isrc;
                if (i_abs != 0) {               // row 0 handled in prep (fp32)
                    float* op = out + (((size_t)b * L_ + i_abs) * H_ + h) * DV_ + il;
                    #pragma unroll
                    for (int nt = 0; nt < 4; ++nt) op[nt * 32] = ov[nt] * sc;
                }
            }
        }
        __syncthreads();   // exch reads done before next segment's staging
    }
}

extern "C" void kernel_launch(void* const* d_in, const int* in_sizes, int n_in,
                              void* d_out, int out_size, void* d_ws, size_t ws_size,
                              hipStream_t stream) {
    const float* q = (const float*)d_in[0];
    const float* k = (const float*)d_in[1];
    const float* v = (const float*)d_in[2];
    // d_in[3] decay_mask (256MB) and d_in[4] intra_decay are recomputed on the fly
    float* out = (float*)d_out;

    unsigned short* kb = (unsigned short*)d_ws;                 // 16 MB
    unsigned short* vt = kb + (size_t)B_ * H_ * L_ * DK_;       // 16 MB

    prep_kernel<<<2080, 256, 0, stream>>>(k, kb, v, vt, q, out);
    retention_kernel<<<256, 512, 0, stream>>>(q, kb, vt, out);
}

// Round 14
// 79.775 us; speedup vs baseline: 1.4256x; 1.1322x over previous
//
#include <hip/hip_runtime.h>
#include <hip/hip_bf16.h>
#include <math.h>

// SelfRetentionV1: B=2,H=16,L=2048,DK=128,DV=128
// out[b,l,h,d] = RMSNorm_d( (QK^T * gamma^(i-j) / max(1,|rowsum|)) @ V )
#define B_ 2
#define H_ 16
#define L_ 2048
#define DK_ 128
#define DV_ 128
#define QBLK 64
#define KVBLK 64

typedef __bf16 bf16x8 __attribute__((ext_vector_type(8)));
typedef float  f32x16 __attribute__((ext_vector_type(16)));

static __device__ __forceinline__ unsigned short f2bf(float f) {
    union { float f; unsigned int u; } x; x.f = f;
    unsigned int r = x.u + 0x7fffu + ((x.u >> 16) & 1u);  // RNE
    return (unsigned short)(r >> 16);
}

// async global->LDS, 16B per lane; LDS dest = wave-uniform base + lane*16
static __device__ __forceinline__ void gload_lds16(const void* g, void* l) {
    __builtin_amdgcn_global_load_lds(
        (const __attribute__((address_space(1))) unsigned int*)g,
        (__attribute__((address_space(3))) unsigned int*)l,
        16, 0, 0);
}

// K tile rows are 256B: swizzle bits 4-6 by row&7 (involution, row bits >=8)
#define KSWZ(d) ((d) ^ ((((d) >> 8) & 7) << 4))
// V tile rows are 128B: row bits >=7
#define VSWZ(d) ((d) ^ ((((d) >> 7) & 7) << 4))

// ---- fused pre-pass: blocks 0..1023 convert K fp32->bf16 SCALED BY
// gamma_h^-(j&63) (folds the per-column decay out of the hot loop);
// 1024..2047 transpose V -> VT[bh][dv][perm(l)] (bit2<->3 perm);
// 2048..2079 fp32 row-0 fixup (retention skips its row-0 store) ----
__global__ void prep_kernel(const float* __restrict__ kin,
                            unsigned short* __restrict__ kb,
                            const float* __restrict__ v,
                            unsigned short* __restrict__ vt,
                            const float* __restrict__ q,
                            float* __restrict__ out) {
    __shared__ unsigned short lds[64][130];   // +2 pad (transpose half only)
    int bid = blockIdx.x;
    if (bid >= 2048) {                 // row-0 fixup, 32 blocks, wave 0 only
        if (threadIdx.x < 64) {
            int bh = bid - 2048;
            int lane = threadIdx.x;
            const float* qp = q   + (size_t)bh * L_ * DK_;
            const float* kp = kin + (size_t)bh * L_ * DK_;
            const float* vp = v   + (size_t)bh * L_ * DV_;
            float part = qp[lane] * kp[lane] + qp[lane + 64] * kp[lane + 64];
            #pragma unroll
            for (int mm = 1; mm < 64; mm <<= 1) part += __shfl_xor(part, mm);
            float cf = part / fmaxf(1.0f, fabsf(part));
            float o0 = cf * vp[lane], o1 = cf * vp[lane + 64];
            float ss = o0 * o0 + o1 * o1;
            #pragma unroll
            for (int mm = 1; mm < 64; mm <<= 1) ss += __shfl_xor(ss, mm);
            float sc = rsqrtf(ss * (1.0f / 128.0f) + 1e-6f);
            int b = bh >> 4, h = bh & 15;
            float* op = out + ((size_t)b * L_ * H_ + h) * DV_;   // i = 0
            op[lane] = o0 * sc;
            op[lane + 64] = o1 * sc;
        }
        return;
    }
    if (bid < 1024) {
        int n4 = B_ * H_ * L_ * DK_ / 4;
        int i = bid * 256 + threadIdx.x;
        int stride = 1024 * 256;
        for (; i < n4; i += stride) {
            // element layout [b][h][l][dk]: j = (i>>5)&2047, h = (i>>16)&15
            int j = (i >> 5) & (L_ - 1);
            int h = (i >> 16) & (H_ - 1);
            float l2g = log1pf(-exp2f((float)(-5 - h))) * 1.44269504088896f;
            float s = exp2f(l2g * -(float)(j & 63));   // gamma^-(j mod 64)
            float4 f = ((const float4*)kin)[i];
            uint2 o;
            o.x = (unsigned)f2bf(f.x * s) | ((unsigned)f2bf(f.y * s) << 16);
            o.y = (unsigned)f2bf(f.z * s) | ((unsigned)f2bf(f.w * s) << 16);
            ((uint2*)kb)[i] = o;
        }
        return;
    }
    int blk = bid - 1024;
    int ltile = blk & (L_/64 - 1);
    int bh = blk / (L_/64);
    const float* vp = v + ((size_t)bh * L_ + (size_t)ltile * 64) * DV_;
    unsigned short* vo = vt + (size_t)bh * DV_ * L_ + ltile * 64;
    int t = threadIdx.x;
    int r0 = t >> 5, c0 = (t & 31) * 4;
    #pragma unroll
    for (int it = 0; it < 8; ++it) {
        int row = r0 + 8 * it;
        float4 f = *(const float4*)(vp + row * DV_ + c0);
        lds[row][c0 + 0] = f2bf(f.x);
        lds[row][c0 + 1] = f2bf(f.y);
        lds[row][c0 + 2] = f2bf(f.z);
        lds[row][c0 + 3] = f2bf(f.w);
    }
    __syncthreads();
    int dvb = t >> 3, seg = t & 7;
    #pragma unroll
    for (int ot = 0; ot < 4; ++ot) {
        int dv = dvb + 32 * ot;
        unsigned short a[8];
        #pragma unroll
        for (int tt = 0; tt < 8; ++tt) {
            int pp = seg * 8 + tt;
            int js = (pp & ~12) | ((pp & 4) << 1) | ((pp & 8) >> 1);  // swap b2,b3
            a[tt] = lds[js][dv];
        }
        uint4 st;
        st.x = (unsigned)a[0] | ((unsigned)a[1] << 16);
        st.y = (unsigned)a[2] | ((unsigned)a[3] << 16);
        st.z = (unsigned)a[4] | ((unsigned)a[5] << 16);
        st.w = (unsigned)a[6] | ((unsigned)a[7] << 16);
        *(uint4*)(vo + (size_t)dv * L_ + seg * 8) = st;
    }
}

// One pipeline round at static buffer offset CUR (0 / 16384), staging the
// next tile into NXT. Protocol = proven r10: vmcnt(8) counted wait (never
// drains the fresh stage), 2 s_barrier. Decay is ONE mul (colfac folded
// into kb by prep); rowsum rides the matrix pipe via mfma(P, ones).
#define ROUND(CUR, NXT)                                                       \
{                                                                             \
    if (jt < itile) {                                                         \
        const char* ksrc = (const char*)(kbp + (size_t)(jt + 1) * KVBLK * DK_);\
        const char* vsrc = (const char*)(vtp + (jt + 1) * KVBLK);             \
        _Pragma("unroll")                                                     \
        for (int is = 0; is < 4; ++is) {                                      \
            gload_lds16(ksrc + koff[is], kLDSw + (NXT) + dwv[is]);            \
            gload_lds16(vsrc + voff[is], vLDSw + (NXT) + dwv[is]);            \
        }                                                                     \
        asm volatile("s_waitcnt vmcnt(8)" ::: "memory");                      \
    } else {                                                                  \
        asm volatile("s_waitcnt vmcnt(0)" ::: "memory");                      \
    }                                                                         \
    asm volatile("s_barrier" ::: "memory");                                   \
    f32x16 s;                                                                 \
    _Pragma("unroll")                                                         \
    for (int e = 0; e < 16; ++e) s[e] = 0.0f;                                 \
    __builtin_amdgcn_s_setprio(1);                                            \
    _Pragma("unroll")                                                         \
    for (int ks = 0; ks < 8; ++ks)                                            \
        s = __builtin_amdgcn_mfma_f32_32x32x16_bf16(                          \
                *(const bf16x8*)(ka[ks] + (CUR)), qf[ks], s, 0, 0, 0);        \
    __builtin_amdgcn_s_setprio(0);                                            \
    float ab = arow;                                                          \
    arow *= gm64i;                                                            \
    float val[16];                                                            \
    if (jt == itile) {                                                        \
        _Pragma("unroll")                                                     \
        for (int r = 0; r < 16; ++r) {                                        \
            float vv = s[r] * ab;                                             \
            val[r] = ((mbits >> r) & 1) ? vv : 0.0f;                          \
        }                                                                     \
    } else {                                                                  \
        _Pragma("unroll")                                                     \
        for (int r = 0; r < 16; ++r) val[r] = s[r] * ab;                      \
    }                                                                         \
    union { bf16x8 v; __bf16 e[8]; } P0, P1;                                  \
    _Pragma("unroll")                                                         \
    for (int e = 0; e < 8; ++e) { P0.e[e] = (__bf16)val[e];                   \
                                  P1.e[e] = (__bf16)val[8 + e]; }             \
    __builtin_amdgcn_s_setprio(1);                                            \
    _Pragma("unroll")                                                         \
    for (int nt = 0; nt < 4; ++nt) {                                          \
        o[nt] = __builtin_amdgcn_mfma_f32_32x32x16_bf16(                      \
                    P0.v, *(const bf16x8*)(va0[nt] + (CUR)), o[nt], 0, 0, 0); \
        o[nt] = __builtin_amdgcn_mfma_f32_32x32x16_bf16(                      \
                    P1.v, *(const bf16x8*)(va1[nt] + (CUR)), o[nt], 0, 0, 0); \
    }                                                                         \
    o4 = __builtin_amdgcn_mfma_f32_32x32x16_bf16(P0.v, onesv, o4, 0, 0, 0);   \
    o4 = __builtin_amdgcn_mfma_f32_32x32x16_bf16(P1.v, onesv, o4, 0, 0, 0);   \
    __builtin_amdgcn_s_setprio(0);                                            \
    asm volatile("s_barrier" ::: "memory");                                   \
}

// ---- main kernel: r10 geometry (best: 84us) -- 4 waves (rh,kh), QBLK=64,
// KVBLK=64, K/V dbuf, balanced q-tile pairs {sp,31-sp}, grid 512 = 2/CU,
// 2 waves/SIMD. This round: VALU-diet only (colfac folded into kb,
// rowsum via ones-MFMA, static dbuf offsets, setprio on MFMA clusters).
__launch_bounds__(256, 2)
__global__ void retention_kernel(const float* __restrict__ q,
                                 const unsigned short* __restrict__ kb,
                                 const unsigned short* __restrict__ vt_,
                                 float* __restrict__ out) {
    __shared__ __align__(16) unsigned short kbuf[2][64 * 128];   // 32 KB
    __shared__ __align__(16) unsigned short vbuf[2][128 * 64];   // 32 KB
    __shared__ float rsx[32];

    // bh->XCD-pinned remap (xcd = bid%8): 4 bh per XCD -> ~4MB K+V ~= L2
    int bid = blockIdx.x;            // 0..511
    int x   = bid & 7;               // XCD id
    int t_  = bid >> 3;              // 0..63
    int hi  = t_ >> 4;               // 0..3
    int sp  = t_ & 15;               // 0..15: q-tile pair (sp, 31-sp)
    int bh = hi * 8 + x;
    int b = bh >> 4, h = bh & 15;

    int tid = threadIdx.x;
    int lane = tid & 63;
    int w = tid >> 6;                   // 0..3
    int rh = w >> 1;                    // q-row half
    int kh = w & 1;                     // kv half
    int il = lane & 31;
    int hl = lane >> 5;

    const unsigned short* kbp = kb  + (size_t)bh * L_ * DK_;
    const unsigned short* vtp = vt_ + (size_t)bh * DV_ * L_;

    // hoisted per-lane stage offsets (loop-invariant)
    int dwv[4], koff[4], voff[4];
    #pragma unroll
    for (int is = 0; is < 4; ++is) {
        int dw = is * 4096 + w * 1024;
        int d  = dw + lane * 16;
        dwv[is]  = dw;
        koff[is] = KSWZ(d);
        int sv   = VSWZ(d);
        voff[is] = (sv >> 7) * (L_ * 2) + (sv & 127);
    }
    char* kLDSw = (char*)&kbuf[0][0];
    char* vLDSw = (char*)&vbuf[0][0];

    float ex = exp2f((float)(-5 - h));
    float log2g = log1pf(-ex) * 1.44269504088896f;
    float gm64i = exp2f(log2g * (-64.0f));

    // diag mask (segment-invariant): keep iff j_local <= i_local
    int icmp = rh * 32 + il - kh * 32;
    unsigned mbits = 0;
    #pragma unroll
    for (int r = 0; r < 16; ++r)
        if (((r & 3) + 8 * (r >> 2) + 4 * hl) <= icmp) mbits |= 1u << r;

    int rswz = (il & 7) << 4;           // read-side XOR (rows == il mod 8)
    int hl16 = hl * 16;

    // hoisted LDS read addresses (buffer picked via +0/+16384 literal)
    const char* ka[8];
    #pragma unroll
    for (int ks = 0; ks < 8; ++ks)
        ka[ks] = (const char*)&kbuf[0][0] + (kh * 32 + il) * 256
                 + ((ks * 32 + hl16) ^ rswz);
    const char* va0[4];
    const char* va1[4];
    #pragma unroll
    for (int nt = 0; nt < 4; ++nt) {
        va0[nt] = (const char*)&vbuf[0][0] + (nt * 32 + il) * 128
                  + ((kh * 64 + hl16) ^ rswz);
        va1[nt] = (const char*)&vbuf[0][0] + (nt * 32 + il) * 128
                  + ((kh * 64 + 32 + hl16) ^ rswz);
    }

    union { bf16x8 v; __bf16 e[8]; } ones_;
    #pragma unroll
    for (int e = 0; e < 8; ++e) ones_.e[e] = (__bf16)1.0f;
    bf16x8 onesv = ones_.v;

    for (int seg = 0; seg < 2; ++seg) {
        int itile = seg ? (31 - sp) : sp;
        int i_base = itile * QBLK + rh * 32;
        int i_row  = i_base + il;       // this lane's q-row

        // ---- Q fragments FIRST (their waits must not drain our stages) ----
        bf16x8 qf[8];
        {
            const float* qp = q + ((size_t)bh * L_ + i_row) * DK_ + hl * 8;
            #pragma unroll
            for (int ks = 0; ks < 8; ++ks) {
                float4 f0 = *(const float4*)(qp + ks * 16);
                float4 f1 = *(const float4*)(qp + ks * 16 + 4);
                union { bf16x8 v; unsigned short u[8]; } A;
                A.u[0]=f2bf(f0.x); A.u[1]=f2bf(f0.y); A.u[2]=f2bf(f0.z); A.u[3]=f2bf(f0.w);
                A.u[4]=f2bf(f1.x); A.u[5]=f2bf(f1.y); A.u[6]=f2bf(f1.z); A.u[7]=f2bf(f1.w);
                qf[ks] = A.v;
            }
        }

        // ---- stage tile 0 into buffer offset 0 ----
        {
            const char* ksrc = (const char*)kbp;
            const char* vsrc = (const char*)vtp;
            #pragma unroll
            for (int is = 0; is < 4; ++is) {
                gload_lds16(ksrc + koff[is], kLDSw + dwv[is]);
                gload_lds16(vsrc + voff[is], vLDSw + dwv[is]);
            }
        }

        // row decay: ab = gamma^(i - jt*64); K' already carries gamma^-(j&63)
        float arow = exp2f(log2g * (float)i_row);

        f32x16 o[4];                    // O^T: lane = dv (il), regs = i-pattern
        #pragma unroll
        for (int nt = 0; nt < 4; ++nt)
            #pragma unroll
            for (int e = 0; e < 16; ++e) o[nt][e] = 0.0f;
        f32x16 o4;                      // rowsums via mfma(P, ones)
        #pragma unroll
        for (int e = 0; e < 16; ++e) o4[e] = 0.0f;

        int jt = 0;
        while (true) {                  // static buffer alternation
            ROUND(0, 16384);
            if (++jt > itile) break;
            ROUND(16384, 0);
            if (++jt > itile) break;
        }

        // ---- cross-kh reduction via LDS (tile buffers dead now) ----
        __syncthreads();   // all tile reads done before buffer reuse
        float* eb = (float*)&kbuf[0][0] + rh * 4096;   // 16KB per rh
        if (kh == 1) {
            #pragma unroll
            for (int nt = 0; nt < 4; ++nt)
                #pragma unroll
                for (int qq = 0; qq < 4; ++qq) {
                    float4 vv = { o[nt][4*qq+0], o[nt][4*qq+1],
                                  o[nt][4*qq+2], o[nt][4*qq+3] };
                    *(float4*)(eb + (nt * 4 + qq) * 256 + lane * 4) = vv;
                }
            if (lane == 0) {
                #pragma unroll
                for (int r = 0; r < 16; ++r) rsx[rh * 16 + r] = o4[r];
            }
        }
        __syncthreads();
        if (kh == 0) {
            #pragma unroll
            for (int nt = 0; nt < 4; ++nt)
                #pragma unroll
                for (int qq = 0; qq < 4; ++qq) {
                    float4 pv = *(const float4*)(eb + (nt * 4 + qq) * 256 + lane * 4);
                    o[nt][4*qq+0] += pv.x; o[nt][4*qq+1] += pv.y;
                    o[nt][4*qq+2] += pv.z; o[nt][4*qq+3] += pv.w;
                }
            #pragma unroll
            for (int r = 0; r < 16; ++r) {
                float rtot = o4[r] + rsx[rh * 16 + r];
                float dn = 1.0f / fmaxf(1.0f, fabsf(rtot));
                float ov[4]; float ss = 0.0f;
                #pragma unroll
                for (int nt = 0; nt < 4; ++nt) { ov[nt] = o[nt][r] * dn; ss += ov[nt]*ov[nt]; }
                ss += __shfl_xor(ss, 1);  ss += __shfl_xor(ss, 2);
                ss += __shfl_xor(ss, 4);  ss += __shfl_xor(ss, 8);
                ss += __shfl_xor(ss, 16);
                float sc = rsqrtf(ss * (1.0f / 128.0f) + 1e-6f);
                int isrc = (r & 3) + 8 * (r >> 2) + 4 * hl;
                int i_abs = i_base + isrc;
                if (i_abs != 0) {               // row 0 handled in prep (fp32)
                    float* op = out + (((size_t)b * L_ + i_abs) * H_ + h) * DV_ + il;
                    #pragma unroll
                    for (int nt = 0; nt < 4; ++nt) op[nt * 32] = ov[nt] * sc;
                }
            }
        }
        __syncthreads();   // exch reads done before next segment's staging
    }
}

extern "C" void kernel_launch(void* const* d_in, const int* in_sizes, int n_in,
                              void* d_out, int out_size, void* d_ws, size_t ws_size,
                              hipStream_t stream) {
    const float* q = (const float*)d_in[0];
    const float* k = (const float*)d_in[1];
    const float* v = (const float*)d_in[2];
    // d_in[3] decay_mask (256MB) and d_in[4] intra_decay are recomputed on the fly
    float* out = (float*)d_out;

    unsigned short* kb = (unsigned short*)d_ws;                 // 16 MB
    unsigned short* vt = kb + (size_t)B_ * H_ * L_ * DK_;       // 16 MB

    prep_kernel<<<2080, 256, 0, stream>>>(k, kb, v, vt, q, out);
    retention_kernel<<<512, 256, 0, stream>>>(q, kb, vt, out);
}